// Round 6
// baseline (6693.648 us; speedup 1.0000x reference)
//
#include <hip/hip_runtime.h>
#include <math.h>

#define E_DIM 64
#define N_E   1024
#define NWAVE 4                 // codebook split: wave w scans codes [256w, 256w+256)
#define CHUNK (N_E / NWAVE)     // 256
#define TILE  16                // codes per staged LDS tile (4 KB)
#define TILES (CHUNK / TILE)    // 16
#define BETA  0.25

// ---------------------------------------------------------------------------
// Numerics (MUST stay bit-identical to the passing round-3/4/5 kernels):
//   nz_i = pairwise-8 sum of rounded z*z        (pw64_sq)
//   h_j  = pairwise-8 sum of rounded e*e        (pw64_sq)
//   m_ij = sequential fp32 FMA chain, k=0..63 ascending, init 0, weights 2*z
//   d_ij = fp32( fp32(nz_i + h_j) - m_ij )      (plain ops, no fma)
//   idx  = argmin_j d, strict <, first index on ties
// Codebook staged global->LDS changes only the data PATH, not values/order.
// Merge over ascending disjoint chunks with strict < == first-index argmin.
//
// ws layout: [0,4096) uint hist[1024]; [4096,4104) double sse; [4112,8208) h
// ---------------------------------------------------------------------------

__device__ __forceinline__ float pw64_sq(const float* v) {
    float r[8];
#pragma unroll
    for (int l = 0; l < 8; ++l) r[l] = v[l] * v[l];
#pragma unroll
    for (int t = 1; t < 8; ++t)
#pragma unroll
        for (int l = 0; l < 8; ++l) r[l] += v[8 * t + l] * v[8 * t + l];
    return ((r[0] + r[1]) + (r[2] + r[3])) + ((r[4] + r[5]) + (r[6] + r[7]));
}

__global__ __launch_bounds__(256) void k_h(const float* __restrict__ cb,
                                           float* __restrict__ h) {
    int j = blockIdx.x * 256 + threadIdx.x;
    if (j < N_E) {
        float e[E_DIM];
        const float4* ep = reinterpret_cast<const float4*>(cb + (size_t)j * E_DIM);
#pragma unroll
        for (int k4 = 0; k4 < E_DIM / 4; ++k4) {
            float4 v = ep[k4];
            e[4 * k4 + 0] = v.x; e[4 * k4 + 1] = v.y;
            e[4 * k4 + 2] = v.z; e[4 * k4 + 3] = v.w;
        }
        h[j] = pw64_sq(e);
    }
}

// Block = 4 waves x 64 lanes; lane owns a row, wave w owns codebook chunk w.
// Codebook flows VMEM -> private LDS tile (double-buffered, T14 async split)
// -> wave-uniform broadcast ds_read_b128. No barriers inside the scan loop.
__global__ __launch_bounds__(256, 4) void k_scan(
    const float* __restrict__ z, const float* __restrict__ cb,
    const float* __restrict__ h,
    float* __restrict__ out_zq, float* __restrict__ out_idx,
    unsigned* __restrict__ hist, double* __restrict__ sse) {
    const int lane = threadIdx.x & 63;
    const int w = __builtin_amdgcn_readfirstlane(threadIdx.x >> 6);
    const int row = blockIdx.x * 64 + lane;

    __shared__ float4 stg[NWAVE][2][TILE * 16];   // 4 x 2 x 4KB = 32 KB
    __shared__ float lb[NWAVE][64];
    __shared__ int   li[NWAVE][64];
    __shared__ int   bidx[64];
    __shared__ float ssep[NWAVE];

    // load z row (16B-aligned), nz from UNSCALED z, then scale by 2 (exact)
    float tz[E_DIM];
    const float4* zp = reinterpret_cast<const float4*>(z + (size_t)row * E_DIM);
#pragma unroll
    for (int k4 = 0; k4 < E_DIM / 4; ++k4) {
        float4 v = zp[k4];
        tz[4 * k4 + 0] = v.x; tz[4 * k4 + 1] = v.y;
        tz[4 * k4 + 2] = v.z; tz[4 * k4 + 3] = v.w;
    }
    const float nz = pw64_sq(tz);
#pragma unroll
    for (int k = 0; k < E_DIM; ++k) tz[k] = 2.0f * tz[k];

    const float4* cb4 = reinterpret_cast<const float4*>(cb);
    const int j0 = w * CHUNK;

    float b0 = INFINITY;
    int bi = 0;
    float4 r0, r1, r2, r3;   // in-flight staging tile (16 VGPRs)

#define LOADT(t) { size_t b = (size_t)(j0 + (t) * TILE) * 16 + lane;            \
                   r0 = cb4[b]; r1 = cb4[b + 64]; r2 = cb4[b + 128]; r3 = cb4[b + 192]; }
#define WRITET(p) { stg[w][p][lane] = r0;       stg[w][p][lane + 64]  = r1;     \
                    stg[w][p][lane + 128] = r2; stg[w][p][lane + 192] = r3; }

    LOADT(0); WRITET(0);
#pragma unroll 1
    for (int t = 0; t < TILES; ++t) {
        if (t + 1 < TILES) LOADT(t + 1);       // issue next tile early (T14)
        const float4* S = &stg[w][t & 1][0];
        const int jb = j0 + t * TILE;
#pragma unroll
        for (int cg = 0; cg < TILE / 4; ++cg) {
            float m0 = 0.f, m1 = 0.f, m2 = 0.f, m3 = 0.f;
#pragma unroll
            for (int k4 = 0; k4 < 16; ++k4) {  // k ascending: chain order preserved
                float4 a = S[(cg * 4 + 0) * 16 + k4];   // uniform addr -> broadcast
                m0 = fmaf(tz[4 * k4 + 0], a.x, m0); m0 = fmaf(tz[4 * k4 + 1], a.y, m0);
                m0 = fmaf(tz[4 * k4 + 2], a.z, m0); m0 = fmaf(tz[4 * k4 + 3], a.w, m0);
                float4 b = S[(cg * 4 + 1) * 16 + k4];
                m1 = fmaf(tz[4 * k4 + 0], b.x, m1); m1 = fmaf(tz[4 * k4 + 1], b.y, m1);
                m1 = fmaf(tz[4 * k4 + 2], b.z, m1); m1 = fmaf(tz[4 * k4 + 3], b.w, m1);
                float4 c = S[(cg * 4 + 2) * 16 + k4];
                m2 = fmaf(tz[4 * k4 + 0], c.x, m2); m2 = fmaf(tz[4 * k4 + 1], c.y, m2);
                m2 = fmaf(tz[4 * k4 + 2], c.z, m2); m2 = fmaf(tz[4 * k4 + 3], c.w, m2);
                float4 d = S[(cg * 4 + 3) * 16 + k4];
                m3 = fmaf(tz[4 * k4 + 0], d.x, m3); m3 = fmaf(tz[4 * k4 + 1], d.y, m3);
                m3 = fmaf(tz[4 * k4 + 2], d.z, m3); m3 = fmaf(tz[4 * k4 + 3], d.w, m3);
            }
            const int j = jb + cg * 4;
            float s0 = (nz + h[j + 0]) - m0;
            float s1 = (nz + h[j + 1]) - m1;
            float s2 = (nz + h[j + 2]) - m2;
            float s3 = (nz + h[j + 3]) - m3;
            if (s0 < b0) { b0 = s0; bi = j + 0; }
            if (s1 < b0) { b0 = s1; bi = j + 1; }
            if (s2 < b0) { b0 = s2; bi = j + 2; }
            if (s3 < b0) { b0 = s3; bi = j + 3; }
        }
        if (t + 1 < TILES) WRITET((t + 1) & 1);   // write-late: vmcnt folds here
    }
#undef LOADT
#undef WRITET

    // merge the 4 chunk-partials per row (ascending chunk order)
    lb[w][lane] = b0;
    li[w][lane] = bi;
    __syncthreads();

    if (threadIdx.x < 64) {
        float b = lb[0][lane];
        int   i = li[0][lane];
#pragma unroll
        for (int c = 1; c < NWAVE; ++c) {
            float bc = lb[c][lane];
            int   ic = li[c][lane];
            if (bc < b) { b = bc; i = ic; }   // strict < keeps lowest chunk/index
        }
        out_idx[row] = (float)i;
        bidx[lane] = i;
    }
    __syncthreads();

    // distributed epilogue: 4 threads per row, 16 dims each
    {
        const int r  = threadIdx.x >> 2;
        const int q  = threadIdx.x & 3;
        const int rw = blockIdx.x * 64 + r;
        const int i2 = bidx[r];
        const float4* cv = cb4 + (size_t)i2 * 16 + q * 4;
        const float4* zv = reinterpret_cast<const float4*>(z + (size_t)rw * E_DIM) + q * 4;
        float* orow = out_zq + (size_t)rw * E_DIM + q * 16;
        float local = 0.f;
#pragma unroll
        for (int u = 0; u < 4; ++u) {
            float4 c = cv[u];
            float4 zz = zv[u];
            orow[4 * u + 0] = c.x; orow[4 * u + 1] = c.y;   // scalar: base 4B-aligned
            orow[4 * u + 2] = c.z; orow[4 * u + 3] = c.w;
            float dx = c.x - zz.x, dy = c.y - zz.y;
            float dz = c.z - zz.z, dw = c.w - zz.w;
            local = fmaf(dx, dx, local);
            local = fmaf(dy, dy, local);
            local = fmaf(dz, dz, local);
            local = fmaf(dw, dw, local);
        }
        if (q == 0) atomicAdd(&hist[i2], 1u);

#pragma unroll
        for (int off = 32; off; off >>= 1) local += __shfl_down(local, off);
        if (lane == 0) ssep[threadIdx.x >> 6] = local;
        __syncthreads();
        if (threadIdx.x == 0) {
            float tsum = ssep[0] + ssep[1] + ssep[2] + ssep[3];
            atomicAdd(sse, (double)tsum);
        }
    }
}

__global__ __launch_bounds__(256) void k_final(
    const unsigned* __restrict__ hist, const double* __restrict__ sse,
    float* __restrict__ out, int nrows) {
    __shared__ double sh[256];
    double acc = 0.0;
    for (int j = threadIdx.x; j < N_E; j += 256) {
        double p = (double)hist[j] / (double)nrows;
        acc += p * log(p + 1e-10);
    }
    sh[threadIdx.x] = acc;
    __syncthreads();
    for (int s = 128; s; s >>= 1) {
        if (threadIdx.x < s) sh[threadIdx.x] += sh[threadIdx.x + s];
        __syncthreads();
    }
    if (threadIdx.x == 0) {
        double ntot = (double)nrows * (double)E_DIM;
        out[0] = (float)((1.0 + BETA) * (*sse) / ntot);               // loss
        out[1 + (size_t)nrows * E_DIM] = (float)exp(-sh[0]);          // perplexity
    }
}

extern "C" void kernel_launch(void* const* d_in, const int* in_sizes, int n_in,
                              void* d_out, int out_size, void* d_ws, size_t ws_size,
                              hipStream_t stream) {
    const float* z  = (const float*)d_in[0];
    const float* cb = (const float*)d_in[1];
    const int nrows = in_sizes[0] / E_DIM;   // 65536
    float* out = (float*)d_out;

    char* ws = (char*)d_ws;
    unsigned* hist = (unsigned*)(ws + 0);
    double*   sse  = (double*)  (ws + 4096);
    float*    h    = (float*)   (ws + 4112);

    float* out_zq  = out + 1;
    float* out_idx = out + 1 + (size_t)nrows * E_DIM + 1;

    hipMemsetAsync(d_ws, 0, 4112, stream);  // hist + sse
    k_h<<<(N_E + 255) / 256, 256, 0, stream>>>(cb, h);
    k_scan<<<nrows / 64, 256, 0, stream>>>(z, cb, h, out_zq, out_idx, hist, sse);
    k_final<<<1, 256, 0, stream>>>(hist, sse, out, nrows);
}

// Round 7
// 170.605 us; speedup vs baseline: 39.2348x; 39.2348x over previous
//
#include <hip/hip_runtime.h>
#include <math.h>

#define E_DIM 64
#define N_E   1024
#define NWAVE 4                 // codebook split: wave w scans codes [256w, 256w+256)
#define CHUNK (N_E / NWAVE)     // 256
#define BETA  0.25

// ---------------------------------------------------------------------------
// Numerics (MUST stay bit-identical to the passing round-3/4/5 kernels):
//   nz_i = pairwise-8 sum of rounded z*z        (pw64_sq)
//   h_j  = pairwise-8 sum of rounded e*e        (pw64_sq)
//   m_ij = sequential fp32 FMA chain, k=0..63 ascending, init 0, weights 2*z
//   d_ij = fp32( fp32(nz_i + h_j) - m_ij )      (plain ops, no fma)
//   idx  = argmin_j d, strict <, first index on ties
// 2 rows/lane shares each fetched code value across two independent chains —
// per-row op sequence unchanged. Merge over ascending disjoint chunks with
// strict < == first-index argmin.
//
// ws layout: [0,4096) uint hist[1024]; [4096,4104) double sse; [4112,8208) h
// ---------------------------------------------------------------------------

__device__ __forceinline__ float pw64_sq(const float* v) {
    float r[8];
#pragma unroll
    for (int l = 0; l < 8; ++l) r[l] = v[l] * v[l];
#pragma unroll
    for (int t = 1; t < 8; ++t)
#pragma unroll
        for (int l = 0; l < 8; ++l) r[l] += v[8 * t + l] * v[8 * t + l];
    return ((r[0] + r[1]) + (r[2] + r[3])) + ((r[4] + r[5]) + (r[6] + r[7]));
}

__global__ __launch_bounds__(256) void k_h(const float* __restrict__ cb,
                                           float* __restrict__ h) {
    int j = blockIdx.x * 256 + threadIdx.x;
    if (j < N_E) {
        float e[E_DIM];
        const float4* ep = reinterpret_cast<const float4*>(cb + (size_t)j * E_DIM);
#pragma unroll
        for (int k4 = 0; k4 < E_DIM / 4; ++k4) {
            float4 v = ep[k4];
            e[4 * k4 + 0] = v.x; e[4 * k4 + 1] = v.y;
            e[4 * k4 + 2] = v.z; e[4 * k4 + 3] = v.w;
        }
        h[j] = pw64_sq(e);
    }
}

// Block = 4 waves x 64 lanes; lane owns TWO rows (rowA = blk*128+lane,
// rowB = rowA+64); wave w owns codebook chunk w (s_load path, wave-uniform).
// __launch_bounds__(256, 2): VGPR cap 256 -> tza+tzb (128) stay in regs.
__global__ __launch_bounds__(256, 2) void k_scan(
    const float* __restrict__ z, const float* __restrict__ cb,
    const float* __restrict__ h,
    float* __restrict__ out_zq, float* __restrict__ out_idx,
    unsigned* __restrict__ hist, double* __restrict__ sse) {
    const int lane = threadIdx.x & 63;
    const int w = __builtin_amdgcn_readfirstlane(threadIdx.x >> 6);
    const int rowA = blockIdx.x * 128 + lane;
    const int rowB = rowA + 64;

    // load both z rows, nz from UNSCALED z, then scale by 2 (exact)
    float tza[E_DIM], tzb[E_DIM];
    {
        const float4* zpA = reinterpret_cast<const float4*>(z + (size_t)rowA * E_DIM);
        const float4* zpB = reinterpret_cast<const float4*>(z + (size_t)rowB * E_DIM);
#pragma unroll
        for (int k4 = 0; k4 < E_DIM / 4; ++k4) {
            float4 a = zpA[k4];
            tza[4 * k4 + 0] = a.x; tza[4 * k4 + 1] = a.y;
            tza[4 * k4 + 2] = a.z; tza[4 * k4 + 3] = a.w;
            float4 b = zpB[k4];
            tzb[4 * k4 + 0] = b.x; tzb[4 * k4 + 1] = b.y;
            tzb[4 * k4 + 2] = b.z; tzb[4 * k4 + 3] = b.w;
        }
    }
    const float nzA = pw64_sq(tza);
    const float nzB = pw64_sq(tzb);
#pragma unroll
    for (int k = 0; k < E_DIM; ++k) { tza[k] = 2.0f * tza[k]; tzb[k] = 2.0f * tzb[k]; }

    float bA = INFINITY, bB = INFINITY;
    int iA = 0, iB = 0;
    const int j0 = w * CHUNK;
#pragma unroll 1
    for (int j = j0; j < j0 + CHUNK; j += 4) {
        const float* c0 = cb + (size_t)j * E_DIM;   // wave-uniform -> s_load
        float mA0 = 0.f, mA1 = 0.f, mA2 = 0.f, mA3 = 0.f;
        float mB0 = 0.f, mB1 = 0.f, mB2 = 0.f, mB3 = 0.f;
#pragma unroll
        for (int k = 0; k < E_DIM; ++k) {
            float e0 = c0[0 * E_DIM + k];
            float e1 = c0[1 * E_DIM + k];
            float e2 = c0[2 * E_DIM + k];
            float e3 = c0[3 * E_DIM + k];
            float wa = tza[k], wb = tzb[k];
            mA0 = fmaf(wa, e0, mA0); mB0 = fmaf(wb, e0, mB0);
            mA1 = fmaf(wa, e1, mA1); mB1 = fmaf(wb, e1, mB1);
            mA2 = fmaf(wa, e2, mA2); mB2 = fmaf(wb, e2, mB2);
            mA3 = fmaf(wa, e3, mA3); mB3 = fmaf(wb, e3, mB3);
        }
        float h0 = h[j + 0], h1 = h[j + 1], h2 = h[j + 2], h3 = h[j + 3];
        float sA0 = (nzA + h0) - mA0;
        float sA1 = (nzA + h1) - mA1;
        float sA2 = (nzA + h2) - mA2;
        float sA3 = (nzA + h3) - mA3;
        if (sA0 < bA) { bA = sA0; iA = j + 0; }
        if (sA1 < bA) { bA = sA1; iA = j + 1; }
        if (sA2 < bA) { bA = sA2; iA = j + 2; }
        if (sA3 < bA) { bA = sA3; iA = j + 3; }
        float sB0 = (nzB + h0) - mB0;
        float sB1 = (nzB + h1) - mB1;
        float sB2 = (nzB + h2) - mB2;
        float sB3 = (nzB + h3) - mB3;
        if (sB0 < bB) { bB = sB0; iB = j + 0; }
        if (sB1 < bB) { bB = sB1; iB = j + 1; }
        if (sB2 < bB) { bB = sB2; iB = j + 2; }
        if (sB3 < bB) { bB = sB3; iB = j + 3; }
    }

    // merge the 4 chunk-partials per row-slot via LDS (ascending chunk order)
    __shared__ float lb[NWAVE][128];
    __shared__ int   li[NWAVE][128];
    __shared__ int   bidx[128];
    lb[w][lane] = bA;       li[w][lane] = iA;
    lb[w][64 + lane] = bB;  li[w][64 + lane] = iB;
    __syncthreads();

    if (threadIdx.x < 128) {
        const int slot = threadIdx.x;
        float b = lb[0][slot];
        int   i = li[0][slot];
#pragma unroll
        for (int c = 1; c < NWAVE; ++c) {
            float bc = lb[c][slot];
            int   ic = li[c][slot];
            if (bc < b) { b = bc; i = ic; }   // strict < keeps lowest chunk/index
        }
        out_idx[blockIdx.x * 128 + slot] = (float)i;
        bidx[slot] = i;
    }
    __syncthreads();

    // epilogue: wave 0 -> slots 0..63 (tza), wave 1 -> slots 64..127 (tzb)
    float local = 0.f;
#define EPI(TZ, SLOT) {                                                          \
        const int slot = (SLOT);                                                 \
        const int rw = blockIdx.x * 128 + slot;                                  \
        const int i2 = bidx[slot];                                               \
        const float4* cv = reinterpret_cast<const float4*>(cb + (size_t)i2 * E_DIM); \
        float* orow = out_zq + (size_t)rw * E_DIM;                               \
        _Pragma("unroll")                                                        \
        for (int k4 = 0; k4 < E_DIM / 4; ++k4) {                                 \
            float4 c = cv[k4];                                                   \
            float zx = 0.5f * TZ[4 * k4 + 0], zy = 0.5f * TZ[4 * k4 + 1];        \
            float zz = 0.5f * TZ[4 * k4 + 2], zw = 0.5f * TZ[4 * k4 + 3];        \
            orow[4 * k4 + 0] = c.x; orow[4 * k4 + 1] = c.y;                      \
            orow[4 * k4 + 2] = c.z; orow[4 * k4 + 3] = c.w;                      \
            float dx = c.x - zx, dy = c.y - zy, dz = c.z - zz, dw = c.w - zw;    \
            local = fmaf(dx, dx, local);                                         \
            local = fmaf(dy, dy, local);                                         \
            local = fmaf(dz, dz, local);                                         \
            local = fmaf(dw, dw, local);                                         \
        }                                                                        \
        atomicAdd(&hist[i2], 1u);                                                \
    }
    if (w == 0) EPI(tza, lane)
    else if (w == 1) EPI(tzb, 64 + lane)
#undef EPI

    // per-wave SSE reduce -> one double atomic per epilogue wave
#pragma unroll
    for (int off = 32; off; off >>= 1) local += __shfl_down(local, off);
    if (w < 2 && lane == 0) atomicAdd(sse, (double)local);
}

__global__ __launch_bounds__(256) void k_final(
    const unsigned* __restrict__ hist, const double* __restrict__ sse,
    float* __restrict__ out, int nrows) {
    __shared__ double sh[256];
    double acc = 0.0;
    for (int j = threadIdx.x; j < N_E; j += 256) {
        double p = (double)hist[j] / (double)nrows;
        acc += p * log(p + 1e-10);
    }
    sh[threadIdx.x] = acc;
    __syncthreads();
    for (int s = 128; s; s >>= 1) {
        if (threadIdx.x < s) sh[threadIdx.x] += sh[threadIdx.x + s];
        __syncthreads();
    }
    if (threadIdx.x == 0) {
        double ntot = (double)nrows * (double)E_DIM;
        out[0] = (float)((1.0 + BETA) * (*sse) / ntot);               // loss
        out[1 + (size_t)nrows * E_DIM] = (float)exp(-sh[0]);          // perplexity
    }
}

extern "C" void kernel_launch(void* const* d_in, const int* in_sizes, int n_in,
                              void* d_out, int out_size, void* d_ws, size_t ws_size,
                              hipStream_t stream) {
    const float* z  = (const float*)d_in[0];
    const float* cb = (const float*)d_in[1];
    const int nrows = in_sizes[0] / E_DIM;   // 65536
    float* out = (float*)d_out;

    char* ws = (char*)d_ws;
    unsigned* hist = (unsigned*)(ws + 0);
    double*   sse  = (double*)  (ws + 4096);
    float*    h    = (float*)   (ws + 4112);

    float* out_zq  = out + 1;
    float* out_idx = out + 1 + (size_t)nrows * E_DIM + 1;

    hipMemsetAsync(d_ws, 0, 4112, stream);  // hist + sse
    k_h<<<(N_E + 255) / 256, 256, 0, stream>>>(cb, h);
    k_scan<<<nrows / 128, 256, 0, stream>>>(z, cb, h, out_zq, out_idx, hist, sse);
    k_final<<<1, 256, 0, stream>>>(hist, sse, out, nrows);
}